// Round 5
// baseline (793.393 us; speedup 1.0000x reference)
//
#include <hip/hip_runtime.h>

#define N_NODES 50000
#define N_EDGES 1600000
#define HDIM 64
#define NLAYERS 3
#define NGRAPH 128
#define BN_EPS 1e-5f

// ---------------- degree histogram: deg[dst[e]]++  (4 edges/thread) ----------
__global__ __launch_bounds__(256) void hist_kernel(
    const int* __restrict__ dst, int* __restrict__ deg)
{
    int e4 = blockIdx.x * 256 + threadIdx.x;
    if (e4 * 4 >= N_EDGES) return;
    int4 d = ((const int4*)dst)[e4];
    atomicAdd(&deg[d.x], 1);
    atomicAdd(&deg[d.y], 1);
    atomicAdd(&deg[d.z], 1);
    atomicAdd(&deg[d.w], 1);
}

// ---------------- single-block exclusive scan of deg -> rowptr, cursor -------
__global__ __launch_bounds__(1024) void scan_kernel(
    const int* __restrict__ deg, int* __restrict__ rowptr, int* __restrict__ cursor)
{
    __shared__ int wsum[16];
    __shared__ int woff[17];
    int tid = threadIdx.x;
    int lane = tid & 63, wid = tid >> 6;
    int run = 0;  // persistent in tid 0's registers
    for (int base = 0; base < N_NODES; base += 1024) {
        int i = base + tid;
        int v = (i < N_NODES) ? deg[i] : 0;
        int incl = v;
        #pragma unroll
        for (int off = 1; off < 64; off <<= 1) {
            int t = __shfl_up(incl, off, 64);
            if (lane >= off) incl += t;
        }
        if (lane == 63) wsum[wid] = incl;
        __syncthreads();
        if (tid == 0) {
            int r = run;
            #pragma unroll
            for (int w = 0; w < 16; ++w) { woff[w] = r; r += wsum[w]; }
            woff[16] = r;
            run = r;
        }
        __syncthreads();
        if (i < N_NODES) {
            int excl = woff[wid] + incl - v;
            rowptr[i] = excl;
            cursor[i] = excl;
        }
        __syncthreads();
    }
    if (tid == 0) rowptr[N_NODES] = run;
}

// ---------------- fill CSR column list (4 edges/thread) ----------------
__global__ __launch_bounds__(256) void fill_kernel(
    const int* __restrict__ src, const int* __restrict__ dst,
    int* __restrict__ cursor, int* __restrict__ col)
{
    int e4 = blockIdx.x * 256 + threadIdx.x;
    if (e4 * 4 >= N_EDGES) return;
    int4 d = ((const int4*)dst)[e4];
    int4 s = ((const int4*)src)[e4];
    int p0 = atomicAdd(&cursor[d.x], 1);
    int p1 = atomicAdd(&cursor[d.y], 1);
    int p2 = atomicAdd(&cursor[d.z], 1);
    int p3 = atomicAdd(&cursor[d.w], 1);
    col[p0] = s.x;
    col[p1] = s.y;
    col[p2] = s.z;
    col[p3] = s.w;
}

// ------ z = (gather(hin) + hin) @ W1 + b1 ; accumulate BN stats --------------
// One wave per row; 4 edges per float4 load; 16-edge unroll = 4 gathers in flight.
__global__ __launch_bounds__(256) void gather_gemm1_kernel(
    const float* __restrict__ hin, const int* __restrict__ rowptr,
    const int* __restrict__ col, const float* __restrict__ W1,
    const float* __restrict__ b1, float* __restrict__ z,
    float* __restrict__ stats /* sum[64], sumsq[64] */)
{
    __shared__ float sW[HDIM * HDIM];
    __shared__ float sIn[4][HDIM];
    __shared__ float sRed[4][HDIM];
    const float4* hin4 = (const float4*)hin;
    int tid = threadIdx.x;
    for (int i = tid; i < HDIM * HDIM; i += 256) sW[i] = W1[i];
    int r = tid >> 6;      // wave id (row slot)
    int c = tid & 63;      // lane
    int sub = c >> 4;      // edge slot 0..3
    int q = c & 15;        // float4 slot: channels q*4 .. q*4+3
    float bias = b1[c];
    float s = 0.f, s2 = 0.f;
    int row0 = blockIdx.x * 16;
    __syncthreads();
    for (int it = 0; it < 4; ++it) {
        int row = row0 + it * 4 + r;
        int e0 = rowptr[row], e1 = rowptr[row + 1];
        float ax = 0.f, ay = 0.f, az = 0.f, aw = 0.f;
        int e = e0;
        for (; e + 16 <= e1; e += 16) {
            int c0 = col[e + sub];
            int c1 = col[e + 4 + sub];
            int c2 = col[e + 8 + sub];
            int c3 = col[e + 12 + sub];
            float4 v0 = hin4[(size_t)c0 * 16 + q];
            float4 v1 = hin4[(size_t)c1 * 16 + q];
            float4 v2 = hin4[(size_t)c2 * 16 + q];
            float4 v3 = hin4[(size_t)c3 * 16 + q];
            ax += (v0.x + v1.x) + (v2.x + v3.x);
            ay += (v0.y + v1.y) + (v2.y + v3.y);
            az += (v0.z + v1.z) + (v2.z + v3.z);
            aw += (v0.w + v1.w) + (v2.w + v3.w);
        }
        if (e + 8 <= e1) {
            int c0 = col[e + sub];
            int c1 = col[e + 4 + sub];
            float4 v0 = hin4[(size_t)c0 * 16 + q];
            float4 v1 = hin4[(size_t)c1 * 16 + q];
            ax += v0.x + v1.x; ay += v0.y + v1.y;
            az += v0.z + v1.z; aw += v0.w + v1.w;
            e += 8;
        }
        if (e + 4 <= e1) {
            int c0 = col[e + sub];
            float4 v0 = hin4[(size_t)c0 * 16 + q];
            ax += v0.x; ay += v0.y; az += v0.z; aw += v0.w;
            e += 4;
        }
        int rem = e1 - e;
        if (sub < rem) {
            int c0 = col[e + sub];
            float4 v0 = hin4[(size_t)c0 * 16 + q];
            ax += v0.x; ay += v0.y; az += v0.z; aw += v0.w;
        }
        // reduce the 4 edge slots (xor 16, then 32)
        ax += __shfl_xor(ax, 16, 64); ay += __shfl_xor(ay, 16, 64);
        az += __shfl_xor(az, 16, 64); aw += __shfl_xor(aw, 16, 64);
        ax += __shfl_xor(ax, 32, 64); ay += __shfl_xor(ay, 32, 64);
        az += __shfl_xor(az, 32, 64); aw += __shfl_xor(aw, 32, 64);
        // + self row ((1+eps)*x with eps=0)
        float4 sv = hin4[(size_t)row * 16 + q];
        ax += sv.x; ay += sv.y; az += sv.z; aw += sv.w;
        if (sub == 0) {
            float4 o; o.x = ax; o.y = ay; o.z = az; o.w = aw;
            *(float4*)&sIn[r][q * 4] = o;
        }
        __syncthreads();
        float acc = bias;
        #pragma unroll
        for (int k = 0; k < HDIM; ++k)
            acc = fmaf(sIn[r][k], sW[k * HDIM + c], acc);
        z[row * HDIM + c] = acc;
        s += acc;
        s2 += acc * acc;
        __syncthreads();
    }
    sRed[r][c] = s;
    __syncthreads();
    if (r == 0)
        atomicAdd(&stats[c], sRed[0][c] + sRed[1][c] + sRed[2][c] + sRed[3][c]);
    __syncthreads();
    sRed[r][c] = s2;
    __syncthreads();
    if (r == 0)
        atomicAdd(&stats[HDIM + c], sRed[0][c] + sRed[1][c] + sRed[2][c] + sRed[3][c]);
}

// --- hout = relu( relu(BN(z)) @ W2 + b2 ), BN scale/shift from raw stats ------
__global__ __launch_bounds__(256) void gemm2_kernel(
    const float* __restrict__ z, const float* __restrict__ W2,
    const float* __restrict__ b2, const float* __restrict__ stats,
    const float* __restrict__ gamma, const float* __restrict__ beta,
    float* __restrict__ hout)
{
    __shared__ float sW[HDIM * HDIM];
    __shared__ float sIn[4][HDIM];
    int tid = threadIdx.x;
    for (int i = tid; i < HDIM * HDIM; i += 256) sW[i] = W2[i];
    int r = tid >> 6, c = tid & 63;
    // BN finalize in-thread
    float mu  = stats[c] / (float)N_NODES;
    float var = stats[HDIM + c] / (float)N_NODES - mu * mu;
    float sc  = gamma[c] * rsqrtf(var + BN_EPS);
    float sh  = beta[c] - mu * sc;
    float bias = b2[c];
    int row0 = blockIdx.x * 16;
    __syncthreads();
    for (int it = 0; it < 4; ++it) {
        int row = row0 + it * 4 + r;
        float v = z[row * HDIM + c] * sc + sh;
        sIn[r][c] = v > 0.f ? v : 0.f;
        __syncthreads();
        float acc = bias;
        #pragma unroll
        for (int k = 0; k < HDIM; ++k)
            acc = fmaf(sIn[r][k], sW[k * HDIM + c], acc);
        acc = acc > 0.f ? acc : 0.f;
        hout[row * HDIM + c] = acc;
        __syncthreads();
    }
}

// ----- graph boundary offsets from sorted batch: gstart[g] = first node of g --
__global__ __launch_bounds__(256) void bounds_kernel(
    const int* __restrict__ batch, int* __restrict__ gstart)
{
    int i = blockIdx.x * 256 + threadIdx.x;
    if (i >= N_NODES) return;
    int g1 = batch[i];
    int g0 = (i == 0) ? -1 : batch[i - 1];
    for (int g = g0 + 1; g <= g1; ++g) gstart[g] = i;
    if (i == N_NODES - 1)
        for (int g = g1 + 1; g <= NGRAPH; ++g) gstart[g] = N_NODES;
}

// ---- fused mean-pool + head: out[g] = relu(mean_g @ Wh1 + bh1) @ Wh2 + bh2 ---
__global__ __launch_bounds__(256) void pool_head_kernel(
    const float* __restrict__ h, const int* __restrict__ gstart,
    const float* __restrict__ Wh1, const float* __restrict__ bh1,
    const float* __restrict__ Wh2, const float* __restrict__ bh2,
    float* __restrict__ out)
{
    __shared__ float sW[HDIM * HDIM];
    __shared__ float sRed[4][HDIM];
    __shared__ float sMean[HDIM];
    int tid = threadIdx.x;
    int r = tid >> 6, c = tid & 63;
    int g = blockIdx.x;
    for (int i = tid; i < HDIM * HDIM; i += 256) sW[i] = Wh1[i];
    int s0 = gstart[g], s1 = gstart[g + 1];
    float acc = 0.f;
    for (int row = s0 + r; row < s1; row += 4)
        acc += h[row * HDIM + c];
    sRed[r][c] = acc;
    __syncthreads();
    if (r == 0) {
        float cntf = (float)(s1 - s0);
        sMean[c] = (sRed[0][c] + sRed[1][c] + sRed[2][c] + sRed[3][c]) /
                   fmaxf(cntf, 1.0f);
    }
    __syncthreads();
    if (r == 0) {
        float a = bh1[c];
        #pragma unroll
        for (int k = 0; k < HDIM; ++k)
            a = fmaf(sMean[k], sW[k * HDIM + c], a);
        a = fmaxf(a, 0.f);
        float p = a * Wh2[c];
        #pragma unroll
        for (int off = 32; off > 0; off >>= 1)
            p += __shfl_down(p, off, 64);
        if (c == 0) out[g] = p + bh2[0];
    }
}

extern "C" void kernel_launch(void* const* d_in, const int* in_sizes, int n_in,
                              void* d_out, int out_size, void* d_ws, size_t ws_size,
                              hipStream_t stream)
{
    const float* x     = (const float*)d_in[0];
    const int*   ei    = (const int*)d_in[1];
    const int*   batch = (const int*)d_in[2];
    const float* W1    = (const float*)d_in[3];
    const float* b1    = (const float*)d_in[4];
    const float* gamma = (const float*)d_in[5];
    const float* beta  = (const float*)d_in[6];
    const float* W2    = (const float*)d_in[7];
    const float* b2    = (const float*)d_in[8];
    const float* Wh1   = (const float*)d_in[9];
    const float* bh1   = (const float*)d_in[10];
    const float* Wh2   = (const float*)d_in[11];
    const float* bh2   = (const float*)d_in[12];
    float* out = (float*)d_out;

    // workspace layout
    float* ws     = (float*)d_ws;
    float* hA     = ws;                             // N*64
    float* hB     = hA + (size_t)N_NODES * HDIM;    // N*64 (z buffer)
    float* scsh   = hB + (size_t)N_NODES * HDIM;    // 128 (unused spare)
    int*   gstart = (int*)(scsh + 2 * HDIM);        // NGRAPH+1
    int*   deg    = gstart + NGRAPH + 1;            // N
    float* stats  = (float*)(deg + N_NODES);        // 3*128 (zeroed with deg)
    int*   rowptr = (int*)(stats + 3 * 2 * HDIM);   // N+1
    int*   cursor = rowptr + N_NODES + 1;           // N
    int*   col    = cursor + N_NODES;               // E

    const int* src = ei;
    const int* dst = ei + N_EDGES;

    int tileGrid  = N_NODES / 16;            // 3125 (exact)
    int edge4Grid = (N_EDGES / 4 + 255) / 256; // 1563
    int nodeGrid  = (N_NODES + 255) / 256;   // 196

    // ---- build CSR (once per call; shared by all 3 layers) ----
    hipMemsetAsync(deg, 0, (N_NODES + 3 * 2 * HDIM) * sizeof(int), stream);
    hist_kernel<<<edge4Grid, 256, 0, stream>>>(dst, deg);
    scan_kernel<<<1, 1024, 0, stream>>>(deg, rowptr, cursor);
    fill_kernel<<<edge4Grid, 256, 0, stream>>>(src, dst, cursor, col);
    bounds_kernel<<<nodeGrid, 256, 0, stream>>>(batch, gstart);

    for (int l = 0; l < NLAYERS; ++l) {
        const float* hin = (l == 0) ? x : hA;
        float* statsl = stats + l * 2 * HDIM;
        gather_gemm1_kernel<<<tileGrid, 256, 0, stream>>>(
            hin, rowptr, col, W1 + l * HDIM * HDIM, b1 + l * HDIM, hB, statsl);
        gemm2_kernel<<<tileGrid, 256, 0, stream>>>(
            hB, W2 + l * HDIM * HDIM, b2 + l * HDIM, statsl,
            gamma + l * HDIM, beta + l * HDIM, hA);
    }

    pool_head_kernel<<<NGRAPH, 256, 0, stream>>>(hA, gstart, Wh1, bh1, Wh2, bh2, out);
}

// Round 6
// 786.590 us; speedup vs baseline: 1.0086x; 1.0086x over previous
//
#include <hip/hip_runtime.h>

#define N_NODES 50000
#define N_EDGES 1600000
#define HDIM 64
#define NLAYERS 3
#define NGRAPH 128
#define BN_EPS 1e-5f

// ---------------- degree histogram: deg[dst[e]]++  (8 edges/thread) ----------
__global__ __launch_bounds__(256) void hist_kernel(
    const int* __restrict__ dst, int* __restrict__ deg)
{
    int e8 = blockIdx.x * 256 + threadIdx.x;
    if (e8 >= N_EDGES / 8) return;
    int4 d0 = ((const int4*)dst)[e8 * 2];
    int4 d1 = ((const int4*)dst)[e8 * 2 + 1];
    atomicAdd(&deg[d0.x], 1);
    atomicAdd(&deg[d0.y], 1);
    atomicAdd(&deg[d0.z], 1);
    atomicAdd(&deg[d0.w], 1);
    atomicAdd(&deg[d1.x], 1);
    atomicAdd(&deg[d1.y], 1);
    atomicAdd(&deg[d1.z], 1);
    atomicAdd(&deg[d1.w], 1);
}

// ---------------- single-block exclusive scan of deg -> rowptr, cursor -------
__global__ __launch_bounds__(1024) void scan_kernel(
    const int* __restrict__ deg, int* __restrict__ rowptr, int* __restrict__ cursor)
{
    __shared__ int wsum[16];
    __shared__ int woff[17];
    int tid = threadIdx.x;
    int lane = tid & 63, wid = tid >> 6;
    int run = 0;  // persistent in tid 0's registers
    for (int base = 0; base < N_NODES; base += 1024) {
        int i = base + tid;
        int v = (i < N_NODES) ? deg[i] : 0;
        int incl = v;
        #pragma unroll
        for (int off = 1; off < 64; off <<= 1) {
            int t = __shfl_up(incl, off, 64);
            if (lane >= off) incl += t;
        }
        if (lane == 63) wsum[wid] = incl;
        __syncthreads();
        if (tid == 0) {
            int r = run;
            #pragma unroll
            for (int w = 0; w < 16; ++w) { woff[w] = r; r += wsum[w]; }
            woff[16] = r;
            run = r;
        }
        __syncthreads();
        if (i < N_NODES) {
            int excl = woff[wid] + incl - v;
            rowptr[i] = excl;
            cursor[i] = excl;
        }
        __syncthreads();
    }
    if (tid == 0) rowptr[N_NODES] = run;
}

// ---------------- fill CSR column list (8 edges/thread) ----------------
__global__ __launch_bounds__(256) void fill_kernel(
    const int* __restrict__ src, const int* __restrict__ dst,
    int* __restrict__ cursor, int* __restrict__ col)
{
    int e8 = blockIdx.x * 256 + threadIdx.x;
    if (e8 >= N_EDGES / 8) return;
    int4 d0 = ((const int4*)dst)[e8 * 2];
    int4 d1 = ((const int4*)dst)[e8 * 2 + 1];
    int4 s0 = ((const int4*)src)[e8 * 2];
    int4 s1 = ((const int4*)src)[e8 * 2 + 1];
    int p0 = atomicAdd(&cursor[d0.x], 1);
    int p1 = atomicAdd(&cursor[d0.y], 1);
    int p2 = atomicAdd(&cursor[d0.z], 1);
    int p3 = atomicAdd(&cursor[d0.w], 1);
    int p4 = atomicAdd(&cursor[d1.x], 1);
    int p5 = atomicAdd(&cursor[d1.y], 1);
    int p6 = atomicAdd(&cursor[d1.z], 1);
    int p7 = atomicAdd(&cursor[d1.w], 1);
    col[p0] = s0.x;
    col[p1] = s0.y;
    col[p2] = s0.z;
    col[p3] = s0.w;
    col[p4] = s1.x;
    col[p5] = s1.y;
    col[p6] = s1.z;
    col[p7] = s1.w;
}

// ------ z = (gather(hin) + hin) @ W1 + b1 ; accumulate BN stats --------------
// One wave per row; 4 edges per float4 load; per-wave LDS slice -> no block
// barriers in the row loop (wave_barrier = compile-time ordering only).
__global__ __launch_bounds__(256) void gather_gemm1_kernel(
    const float* __restrict__ hin, const int* __restrict__ rowptr,
    const int* __restrict__ col, const float* __restrict__ W1,
    const float* __restrict__ b1, float* __restrict__ z,
    float* __restrict__ stats /* sum[64], sumsq[64] */)
{
    __shared__ float sW[HDIM * HDIM];
    __shared__ float sIn[4][HDIM];
    __shared__ float sRed[4][HDIM];
    const float4* hin4 = (const float4*)hin;
    int tid = threadIdx.x;
    for (int i = tid; i < HDIM * HDIM; i += 256) sW[i] = W1[i];
    int r = tid >> 6;      // wave id (row slot)
    int c = tid & 63;      // lane
    int sub = c >> 4;      // edge slot 0..3
    int q = c & 15;        // float4 slot: channels q*4 .. q*4+3
    float bias = b1[c];
    float s = 0.f, s2 = 0.f;
    int row0 = blockIdx.x * 16;
    __syncthreads();       // sW visible to all waves
    for (int it = 0; it < 4; ++it) {
        int row = row0 + it * 4 + r;
        int e0 = rowptr[row], e1 = rowptr[row + 1];
        float ax = 0.f, ay = 0.f, az = 0.f, aw = 0.f;
        int e = e0;
        for (; e + 8 <= e1; e += 8) {
            int c0 = col[e + sub];
            int c1 = col[e + 4 + sub];
            float4 v0 = hin4[(size_t)c0 * 16 + q];
            float4 v1 = hin4[(size_t)c1 * 16 + q];
            ax += v0.x + v1.x; ay += v0.y + v1.y;
            az += v0.z + v1.z; aw += v0.w + v1.w;
        }
        if (e + 4 <= e1) {
            int c0 = col[e + sub];
            float4 v0 = hin4[(size_t)c0 * 16 + q];
            ax += v0.x; ay += v0.y; az += v0.z; aw += v0.w;
            e += 4;
        }
        int rem = e1 - e;
        if (sub < rem) {
            int c0 = col[e + sub];
            float4 v0 = hin4[(size_t)c0 * 16 + q];
            ax += v0.x; ay += v0.y; az += v0.z; aw += v0.w;
        }
        // reduce the 4 edge slots (xor 16, then 32)
        ax += __shfl_xor(ax, 16, 64); ay += __shfl_xor(ay, 16, 64);
        az += __shfl_xor(az, 16, 64); aw += __shfl_xor(aw, 16, 64);
        ax += __shfl_xor(ax, 32, 64); ay += __shfl_xor(ay, 32, 64);
        az += __shfl_xor(az, 32, 64); aw += __shfl_xor(aw, 32, 64);
        // + self row ((1+eps)*x with eps=0)
        float4 sv = hin4[(size_t)row * 16 + q];
        ax += sv.x; ay += sv.y; az += sv.z; aw += sv.w;
        if (sub == 0) {
            float4 o; o.x = ax; o.y = ay; o.z = az; o.w = aw;
            *(float4*)&sIn[r][q * 4] = o;
        }
        __builtin_amdgcn_wave_barrier();  // same-wave LDS producer->consumer
        float acc = bias;
        #pragma unroll
        for (int k = 0; k < HDIM; ++k)
            acc = fmaf(sIn[r][k], sW[k * HDIM + c], acc);
        z[row * HDIM + c] = acc;
        s += acc;
        s2 += acc * acc;
        __builtin_amdgcn_wave_barrier();  // reads done before next it's write
    }
    sRed[r][c] = s;
    __syncthreads();
    if (r == 0)
        atomicAdd(&stats[c], sRed[0][c] + sRed[1][c] + sRed[2][c] + sRed[3][c]);
    __syncthreads();
    sRed[r][c] = s2;
    __syncthreads();
    if (r == 0)
        atomicAdd(&stats[HDIM + c], sRed[0][c] + sRed[1][c] + sRed[2][c] + sRed[3][c]);
}

// --- hout = relu( relu(BN(z)) @ W2 + b2 ), BN scale/shift from raw stats ------
__global__ __launch_bounds__(256) void gemm2_kernel(
    const float* __restrict__ z, const float* __restrict__ W2,
    const float* __restrict__ b2, const float* __restrict__ stats,
    const float* __restrict__ gamma, const float* __restrict__ beta,
    float* __restrict__ hout)
{
    __shared__ float sW[HDIM * HDIM];
    __shared__ float sIn[4][HDIM];
    int tid = threadIdx.x;
    for (int i = tid; i < HDIM * HDIM; i += 256) sW[i] = W2[i];
    int r = tid >> 6, c = tid & 63;
    // BN finalize in-thread
    float mu  = stats[c] / (float)N_NODES;
    float var = stats[HDIM + c] / (float)N_NODES - mu * mu;
    float sc  = gamma[c] * rsqrtf(var + BN_EPS);
    float sh  = beta[c] - mu * sc;
    float bias = b2[c];
    int row0 = blockIdx.x * 16;
    __syncthreads();       // sW visible to all waves
    for (int it = 0; it < 4; ++it) {
        int row = row0 + it * 4 + r;
        float v = z[row * HDIM + c] * sc + sh;
        sIn[r][c] = v > 0.f ? v : 0.f;
        __builtin_amdgcn_wave_barrier();  // same-wave LDS producer->consumer
        float acc = bias;
        #pragma unroll
        for (int k = 0; k < HDIM; ++k)
            acc = fmaf(sIn[r][k], sW[k * HDIM + c], acc);
        acc = acc > 0.f ? acc : 0.f;
        hout[row * HDIM + c] = acc;
        __builtin_amdgcn_wave_barrier();
    }
}

// ----- graph boundary offsets from sorted batch: gstart[g] = first node of g --
__global__ __launch_bounds__(256) void bounds_kernel(
    const int* __restrict__ batch, int* __restrict__ gstart)
{
    int i = blockIdx.x * 256 + threadIdx.x;
    if (i >= N_NODES) return;
    int g1 = batch[i];
    int g0 = (i == 0) ? -1 : batch[i - 1];
    for (int g = g0 + 1; g <= g1; ++g) gstart[g] = i;
    if (i == N_NODES - 1)
        for (int g = g1 + 1; g <= NGRAPH; ++g) gstart[g] = N_NODES;
}

// ---- fused mean-pool + head: out[g] = relu(mean_g @ Wh1 + bh1) @ Wh2 + bh2 ---
__global__ __launch_bounds__(256) void pool_head_kernel(
    const float* __restrict__ h, const int* __restrict__ gstart,
    const float* __restrict__ Wh1, const float* __restrict__ bh1,
    const float* __restrict__ Wh2, const float* __restrict__ bh2,
    float* __restrict__ out)
{
    __shared__ float sW[HDIM * HDIM];
    __shared__ float sRed[4][HDIM];
    __shared__ float sMean[HDIM];
    int tid = threadIdx.x;
    int r = tid >> 6, c = tid & 63;
    int g = blockIdx.x;
    for (int i = tid; i < HDIM * HDIM; i += 256) sW[i] = Wh1[i];
    int s0 = gstart[g], s1 = gstart[g + 1];
    float acc = 0.f;
    for (int row = s0 + r; row < s1; row += 4)
        acc += h[row * HDIM + c];
    sRed[r][c] = acc;
    __syncthreads();
    if (r == 0) {
        float cntf = (float)(s1 - s0);
        sMean[c] = (sRed[0][c] + sRed[1][c] + sRed[2][c] + sRed[3][c]) /
                   fmaxf(cntf, 1.0f);
    }
    __syncthreads();
    if (r == 0) {
        float a = bh1[c];
        #pragma unroll
        for (int k = 0; k < HDIM; ++k)
            a = fmaf(sMean[k], sW[k * HDIM + c], a);
        a = fmaxf(a, 0.f);
        float p = a * Wh2[c];
        #pragma unroll
        for (int off = 32; off > 0; off >>= 1)
            p += __shfl_down(p, off, 64);
        if (c == 0) out[g] = p + bh2[0];
    }
}

extern "C" void kernel_launch(void* const* d_in, const int* in_sizes, int n_in,
                              void* d_out, int out_size, void* d_ws, size_t ws_size,
                              hipStream_t stream)
{
    const float* x     = (const float*)d_in[0];
    const int*   ei    = (const int*)d_in[1];
    const int*   batch = (const int*)d_in[2];
    const float* W1    = (const float*)d_in[3];
    const float* b1    = (const float*)d_in[4];
    const float* gamma = (const float*)d_in[5];
    const float* beta  = (const float*)d_in[6];
    const float* W2    = (const float*)d_in[7];
    const float* b2    = (const float*)d_in[8];
    const float* Wh1   = (const float*)d_in[9];
    const float* bh1   = (const float*)d_in[10];
    const float* Wh2   = (const float*)d_in[11];
    const float* bh2   = (const float*)d_in[12];
    float* out = (float*)d_out;

    // workspace layout
    float* ws     = (float*)d_ws;
    float* hA     = ws;                             // N*64
    float* hB     = hA + (size_t)N_NODES * HDIM;    // N*64 (z buffer)
    float* scsh   = hB + (size_t)N_NODES * HDIM;    // 128 (unused spare)
    int*   gstart = (int*)(scsh + 2 * HDIM);        // NGRAPH+1
    int*   deg    = gstart + NGRAPH + 1;            // N
    float* stats  = (float*)(deg + N_NODES);        // 3*128 (zeroed with deg)
    int*   rowptr = (int*)(stats + 3 * 2 * HDIM);   // N+1
    int*   cursor = rowptr + N_NODES + 1;           // N
    int*   col    = cursor + N_NODES;               // E

    const int* src = ei;
    const int* dst = ei + N_EDGES;

    int tileGrid  = N_NODES / 16;              // 3125 (exact)
    int edge8Grid = (N_EDGES / 8 + 255) / 256; // 782
    int nodeGrid  = (N_NODES + 255) / 256;     // 196

    // ---- build CSR (once per call; shared by all 3 layers) ----
    hipMemsetAsync(deg, 0, (N_NODES + 3 * 2 * HDIM) * sizeof(int), stream);
    hist_kernel<<<edge8Grid, 256, 0, stream>>>(dst, deg);
    scan_kernel<<<1, 1024, 0, stream>>>(deg, rowptr, cursor);
    fill_kernel<<<edge8Grid, 256, 0, stream>>>(src, dst, cursor, col);
    bounds_kernel<<<nodeGrid, 256, 0, stream>>>(batch, gstart);

    for (int l = 0; l < NLAYERS; ++l) {
        const float* hin = (l == 0) ? x : hA;
        float* statsl = stats + l * 2 * HDIM;
        gather_gemm1_kernel<<<tileGrid, 256, 0, stream>>>(
            hin, rowptr, col, W1 + l * HDIM * HDIM, b1 + l * HDIM, hB, statsl);
        gemm2_kernel<<<tileGrid, 256, 0, stream>>>(
            hB, W2 + l * HDIM * HDIM, b2 + l * HDIM, statsl,
            gamma + l * HDIM, beta + l * HDIM, hA);
    }

    pool_head_kernel<<<NGRAPH, 256, 0, stream>>>(hA, gstart, Wh1, bh1, Wh2, bh2, out);
}